// Round 8
// baseline (214.320 us; speedup 1.0000x reference)
//
#include <hip/hip_runtime.h>
#include <math.h>

// SemanticDriftCoeff — bf16 MFMA GEMMs with 64x128 C-tiles, BK=64, 24 KB LDS
// -> 4+ blocks/CU co-resident (grids 1056/1120/1056), phase-staggered starts.
// XOR-swizzled LDS (0 bank conflicts), atomic-free split-K gemm2.
// ws: floats [0,T) invnorm, [T,2T) L, [2T,3T) dmaxu, [3T,4T) gn2, [4T,5T) dist2,
// [5T, 5T+4*T*D) gpart fp32; then ushort hb[T*D], hbT[D*T], gb[T*D], W[T*T].

#define T_ 4096
#define D_ 896

typedef float f32x4 __attribute__((ext_vector_type(4)));
typedef unsigned short u16x8 __attribute__((ext_vector_type(8)));
typedef __bf16 bf16x8 __attribute__((ext_vector_type(8)));

union V16 { uint4 u; u16x8 v; };

__device__ __forceinline__ u16x8 ld16(const unsigned short* p) {
  V16 x; x.u = *(const uint4*)p; return x.v;
}
__device__ __forceinline__ unsigned short f2bf(float f) {  // RNE float->bf16 bits
  unsigned int u = __float_as_uint(f);
  u += 0x7FFFu + ((u >> 16) & 1u);
  return (unsigned short)(u >> 16);
}
__device__ __forceinline__ float bf2f(unsigned short b) {
  return __uint_as_float(((unsigned int)b) << 16);
}
__device__ __forceinline__ f32x4 mfma16(u16x8 a, u16x8 b, f32x4 c) {
  return __builtin_amdgcn_mfma_f32_16x16x32_bf16(
      __builtin_bit_cast(bf16x8, a), __builtin_bit_cast(bf16x8, b), c, 0, 0, 0);
}

typedef __attribute__((address_space(1))) const void glob_cv;
typedef __attribute__((address_space(3))) void lds_v;
__device__ __forceinline__ void gload16(const void* g, void* l) {
  __builtin_amdgcn_global_load_lds((glob_cv*)g, (lds_v*)l, 16, 0, 0);
}

// Stage an NROWSx64 bf16 tile with XOR group swizzle: logical 16B-group pg of
// row r is fetched from global group pg^(r&7). LDS dst contiguous in lane
// order (global_load_lds constraint); permutation applied to the GLOBAL addr.
template <int ITERS>  // ITERS = NROWS/32
__device__ __forceinline__ void stage_sw(const unsigned short* __restrict__ g0,
                                         int stride, unsigned short* lds0, int tid) {
  #pragma unroll
  for (int it = 0; it < ITERS; ++it) {
    const int e = it * 256 + tid;        // 16B unit index
    const int row = e >> 3, pg = e & 7;
    const int gg = pg ^ (row & 7);
    gload16(g0 + (size_t)row * stride + gg * 8, lds0 + e * 8);
  }
}

// One 64-deep K-chunk of 64x128 MFMA work (wave wn owns s-cols [wn*32,wn*32+32)).
__device__ __forceinline__ void mfma_chunk(const unsigned short* As,
    const unsigned short* Bs, int wn, int tcol, int quad, f32x4 acc[4][2]) {
  const int sx = tcol & 7;
  #pragma unroll
  for (int kk = 0; kk < 2; ++kk) {
    u16x8 af[4], bf[2];
    const int go = ((kk * 4 + quad) ^ sx) * 8;
    #pragma unroll
    for (int mi = 0; mi < 4; ++mi)
      af[mi] = ld16(&As[(mi * 16 + tcol) * 64 + go]);
    #pragma unroll
    for (int ni = 0; ni < 2; ++ni)
      bf[ni] = ld16(&Bs[(wn * 32 + ni * 16 + tcol) * 64 + go]);
    #pragma unroll
    for (int mi = 0; mi < 4; ++mi)
      #pragma unroll
      for (int ni = 0; ni < 2; ++ni)
        acc[mi][ni] = mfma16(af[mi], bf[ni], acc[mi][ni]);
  }
}

// decode b -> (ti, sj): 64 t-tiles of 64 rows, row ti has ceil((ti+1)/2) s-tiles
// of 128. Cum: C(2m)=m(m+1), C(2m+1)=(m+1)^2.
__device__ __forceinline__ void tri64_decode(int b, int& ti, int& sj) {
  int m = (int)sqrtf((float)b);
  while ((m + 1) * (m + 1) <= b) ++m;
  while (m * m > b) --m;
  if (b >= m * (m + 1)) { ti = 2 * m;     sj = b - m * (m + 1); }
  else                  { ti = 2 * m - 1; sj = b - m * m; }
}

__device__ __forceinline__ void stagger(int bx) {
  const int ph = bx & 3;                 // de-phase co-resident blocks (convoy fix)
  for (int i = 0; i < ph; ++i) __builtin_amdgcn_s_sleep(15);
}

// ---------- prep: invnorm + bf16 normalized rows ----------
__global__ __launch_bounds__(256) void k_prep(const float* __restrict__ x,
    float* __restrict__ invnorm, unsigned short* __restrict__ hb) {
  const int t = (int)blockIdx.x, tid = (int)threadIdx.x;
  const int c = tid * 4;
  float4 v = make_float4(0.f, 0.f, 0.f, 0.f);
  float s = 0.f;
  if (c < D_) {
    v = *(const float4*)(x + (size_t)t * D_ + c);
    s = v.x * v.x + v.y * v.y + v.z * v.z + v.w * v.w;
  }
  __shared__ float sb[4];
  __shared__ float sinv;
  #pragma unroll
  for (int off = 32; off > 0; off >>= 1) s += __shfl_down(s, off, 64);
  if ((tid & 63) == 0) sb[tid >> 6] = s;
  __syncthreads();
  if (tid == 0) {
    const float tot = sb[0] + sb[1] + sb[2] + sb[3];
    const float iv = 1.0f / fmaxf(sqrtf(tot), 1e-12f);
    invnorm[t] = iv; sinv = iv;
  }
  __syncthreads();
  if (c < D_) {
    const float iv = sinv;
    *(ushort4*)(hb + (size_t)t * D_ + c) = make_ushort4(
        f2bf(v.x * iv), f2bf(v.y * iv), f2bf(v.z * iv), f2bf(v.w * iv));
  }
}

// ---------- 32x32 bf16 transpose hb -> hbT ----------
__global__ __launch_bounds__(256) void k_transp(const unsigned short* __restrict__ hb,
                                                unsigned short* __restrict__ hbT) {
  __shared__ unsigned short Ts[32][36];
  const int t0 = (int)blockIdx.x * 32, d0 = (int)blockIdx.y * 32;
  const int r = (int)threadIdx.x >> 3, c = ((int)threadIdx.x & 7) * 4;
  const ushort4 v = *(const ushort4*)(hb + (size_t)(t0 + r) * D_ + d0 + c);
  Ts[r][c] = v.x; Ts[r][c + 1] = v.y; Ts[r][c + 2] = v.z; Ts[r][c + 3] = v.w;
  __syncthreads();
  const ushort4 o = make_ushort4(Ts[c][r], Ts[c + 1][r], Ts[c + 2][r], Ts[c + 3][r]);
  *(ushort4*)(hbT + (size_t)(d0 + r) * T_ + t0 + c) = o;
}

// ---------- GEMM1: S = h h^T (1056 causal 64x128 tiles); W = exp, L = rowsum ----------
__global__ __launch_bounds__(256, 4) void k_gemm1(const unsigned short* __restrict__ hb,
    unsigned short* __restrict__ W, float* __restrict__ L) {
  int ti, sj;
  tri64_decode((int)blockIdx.x, ti, sj);
  const int t0 = ti * 64, s0 = sj * 128;
  __shared__ unsigned short As[64 * 64];
  __shared__ unsigned short Bs[128 * 64];
  const int tid = (int)threadIdx.x;
  const int lane = tid & 63, wn = tid >> 6;
  const int tcol = lane & 15, quad = lane >> 4;
  f32x4 acc[4][2] = {};
  stagger((int)blockIdx.x);
  for (int kc = 0; kc < 14; ++kc) {
    __syncthreads();
    stage_sw<2>(hb + (size_t)t0 * D_ + kc * 64, D_, As, tid);
    stage_sw<4>(hb + (size_t)s0 * D_ + kc * 64, D_, Bs, tid);
    __syncthreads();
    mfma_chunk(As, Bs, wn, tcol, quad, acc);
  }
  #pragma unroll
  for (int mi = 0; mi < 4; ++mi) {
    #pragma unroll
    for (int r = 0; r < 4; ++r) {
      const int t = t0 + mi * 16 + quad * 4 + r;
      float lsum = 0.f;
      #pragma unroll
      for (int ni = 0; ni < 2; ++ni) {
        const int s = s0 + wn * 32 + ni * 16 + tcol;
        const int dt = t - s;
        float wval = 0.f;
        if (dt >= 0)
          wval = __expf(acc[mi][ni][r] * (__expf(-0.1f * (float)dt) * 0.033407657f));
        const unsigned short wb = f2bf(wval);
        W[(size_t)t * T_ + s] = wb;
        lsum += bf2f(wb);
      }
      lsum += __shfl_xor(lsum, 1, 64);
      lsum += __shfl_xor(lsum, 2, 64);
      lsum += __shfl_xor(lsum, 4, 64);
      lsum += __shfl_xor(lsum, 8, 64);
      if (tcol == 0) atomicAdd(&L[t], lsum);
    }
  }
}

// ---------- GEMM2 (split-K, atomic-free): gpart[z][t][d] = sum_s W[t][s] hbT[d][s] ----------
__global__ __launch_bounds__(256, 4) void k_gemm2(const unsigned short* __restrict__ W,
    const unsigned short* __restrict__ hbT, float* __restrict__ gpart) {
  const int tj = (int)blockIdx.x, dj = (int)blockIdx.y, z = (int)blockIdx.z;
  const int nk = tj + 1;                // causal 64-chunks: s < t0+64
  const int k0 = z * 16;
  if (k0 >= nk) return;
  const int k1 = min(k0 + 16, nk);
  const int t0 = tj * 64, d0 = dj * 128;
  __shared__ unsigned short As[64 * 64];
  __shared__ unsigned short Bs[128 * 64];
  const int tid = (int)threadIdx.x;
  const int lane = tid & 63, wn = tid >> 6;
  const int tcol = lane & 15, quad = lane >> 4;
  f32x4 acc[4][2] = {};
  stagger((int)blockIdx.x + (int)blockIdx.y);
  for (int kc = k0; kc < k1; ++kc) {
    __syncthreads();
    stage_sw<2>(W + (size_t)t0 * T_ + kc * 64, T_, As, tid);    // A[m=t][k=s]
    stage_sw<4>(hbT + (size_t)d0 * T_ + kc * 64, T_, Bs, tid);  // B[n=d][k=s]
    __syncthreads();
    mfma_chunk(As, Bs, wn, tcol, quad, acc);
  }
  float* base = gpart + (size_t)z * T_ * D_;
  #pragma unroll
  for (int mi = 0; mi < 4; ++mi) {
    #pragma unroll
    for (int ni = 0; ni < 2; ++ni) {
      const int t = t0 + mi * 16 + quad * 4;
      const int d = d0 + wn * 32 + ni * 16 + tcol;
      float* gp = base + (size_t)t * D_ + d;
      gp[0]      = acc[mi][ni][0];
      gp[D_]     = acc[mi][ni][1];
      gp[2 * D_] = acc[mi][ni][2];
      gp[3 * D_] = acc[mi][ni][3];
    }
  }
}

// ---------- gfin: g = (sum_z gpart)/L; gb = bf16(g); gn2; dist2 ----------
__global__ __launch_bounds__(256) void k_gfin(const float* __restrict__ gpart,
    const float* __restrict__ L, const float* __restrict__ x,
    const float* __restrict__ invnorm, unsigned short* __restrict__ gb,
    float* __restrict__ gn2, float* __restrict__ dist2) {
  const int t = (int)blockIdx.x, tid = (int)threadIdx.x;
  const int nz = ((t >> 6) + 16) >> 4;   // ceil(nk/16), nk = (t>>6)+1
  const float invL = 1.0f / L[t];
  const float inr = invnorm[t];
  float sg = 0.f, sd = 0.f;
  const int c = tid * 4;
  if (c < D_) {
    float4 gv = make_float4(0.f, 0.f, 0.f, 0.f);
    for (int z = 0; z < nz; ++z) {
      const float4 p = *(const float4*)(gpart + (size_t)z * T_ * D_ + (size_t)t * D_ + c);
      gv.x += p.x; gv.y += p.y; gv.z += p.z; gv.w += p.w;
    }
    gv.x *= invL; gv.y *= invL; gv.z *= invL; gv.w *= invL;
    *(ushort4*)(gb + (size_t)t * D_ + c) =
        make_ushort4(f2bf(gv.x), f2bf(gv.y), f2bf(gv.z), f2bf(gv.w));
    const float4 hv = *(const float4*)(x + (size_t)t * D_ + c);
    const float e0 = hv.x * inr - gv.x, e1 = hv.y * inr - gv.y;
    const float e2 = hv.z * inr - gv.z, e3 = hv.w * inr - gv.w;
    sg = gv.x * gv.x + gv.y * gv.y + gv.z * gv.z + gv.w * gv.w;
    sd = e0 * e0 + e1 * e1 + e2 * e2 + e3 * e3;
  }
  __shared__ float sb1[4], sb2[4];
  #pragma unroll
  for (int off = 32; off > 0; off >>= 1) {
    sg += __shfl_down(sg, off, 64);
    sd += __shfl_down(sd, off, 64);
  }
  if ((tid & 63) == 0) { sb1[tid >> 6] = sg; sb2[tid >> 6] = sd; }
  __syncthreads();
  if (tid == 0) {
    gn2[t]   = sb1[0] + sb1[1] + sb1[2] + sb1[3];
    dist2[t] = sb2[0] + sb2[1] + sb2[2] + sb2[3];
  }
}

// ---------- GEMM3: cross = g h^T (1056 causal tiles); causal row-max of d2 ----------
__global__ __launch_bounds__(256, 4) void k_gemm3(const unsigned short* __restrict__ gb,
    const unsigned short* __restrict__ hb, const float* __restrict__ gn2,
    unsigned int* __restrict__ dmaxu) {
  int ti, sj;
  tri64_decode((int)blockIdx.x, ti, sj);
  const int t0 = ti * 64, s0 = sj * 128;
  __shared__ unsigned short As[64 * 64];
  __shared__ unsigned short Bs[128 * 64];
  const int tid = (int)threadIdx.x;
  const int lane = tid & 63, wn = tid >> 6;
  const int tcol = lane & 15, quad = lane >> 4;
  f32x4 acc[4][2] = {};
  stagger((int)blockIdx.x);
  for (int kc = 0; kc < 14; ++kc) {
    __syncthreads();
    stage_sw<2>(gb + (size_t)t0 * D_ + kc * 64, D_, As, tid);
    stage_sw<4>(hb + (size_t)s0 * D_ + kc * 64, D_, Bs, tid);
    __syncthreads();
    mfma_chunk(As, Bs, wn, tcol, quad, acc);
  }
  #pragma unroll
  for (int mi = 0; mi < 4; ++mi) {
    #pragma unroll
    for (int r = 0; r < 4; ++r) {
      const int t = t0 + mi * 16 + quad * 4 + r;
      const float gn = gn2[t];
      float m2 = 0.f;
      #pragma unroll
      for (int ni = 0; ni < 2; ++ni) {
        const int s = s0 + wn * 32 + ni * 16 + tcol;
        if (t - s >= 0)
          m2 = fmaxf(m2, fmaxf(1.0f - 2.0f * acc[mi][ni][r] + gn, 1e-24f));
      }
      m2 = fmaxf(m2, __shfl_xor(m2, 1, 64));
      m2 = fmaxf(m2, __shfl_xor(m2, 2, 64));
      m2 = fmaxf(m2, __shfl_xor(m2, 4, 64));
      m2 = fmaxf(m2, __shfl_xor(m2, 8, 64));
      if (tcol == 0) atomicMax(&dmaxu[t], __float_as_uint(m2));
    }
  }
}

__global__ __launch_bounds__(256) void k_final(const float* __restrict__ m_t,
    const float* __restrict__ c_t, const float* __restrict__ d_t,
    const float* __restrict__ mu, const float* __restrict__ dist2,
    const unsigned int* __restrict__ dmaxu, float* __restrict__ out) {
  const int t = (int)blockIdx.x * 256 + (int)threadIdx.x;
  if (t >= T_) return;
  float ratio;
  if (t == 0) {
    ratio = 0.f;  // ref: dist~1e-12, dist_max<1e-6 -> 1.0 => ratio ~0
  } else {
    float dmax = sqrtf(__uint_as_float(dmaxu[t]));
    if (dmax < 1e-6f) dmax = 1.0f;
    ratio = sqrtf(fmaxf(dist2[t], 1e-24f)) / (dmax + 1e-8f);
  }
  const float stab = 1.0f - 0.3f * c_t[t] + 0.2f * d_t[t];
  const float xi = 1.0f - mu[0] * m_t[t];
  out[t] = fminf(fmaxf(ratio * stab * xi, 0.f), 1.f);
}

extern "C" void kernel_launch(void* const* d_in, const int* in_sizes, int n_in,
                              void* d_out, int out_size, void* d_ws, size_t ws_size,
                              hipStream_t stream) {
  const float* x   = (const float*)d_in[0];
  const float* m_t = (const float*)d_in[1];
  const float* c_t = (const float*)d_in[2];
  const float* d_t = (const float*)d_in[3];
  const float* mu  = (const float*)d_in[4];
  float* out = (float*)d_out;

  float* ws = (float*)d_ws;
  float* invnorm = ws;                                         // [T]
  float* L       = ws + T_;                                    // [T]
  unsigned int* dmaxu = (unsigned int*)(ws + 2 * (size_t)T_);  // [T]
  float* gn2     = ws + 3 * (size_t)T_;                        // [T]
  float* dist2   = ws + 4 * (size_t)T_;                        // [T]
  float* gpart   = ws + 5 * (size_t)T_;                        // [4][T*D] fp32
  unsigned short* hb  = (unsigned short*)(gpart + 4 * (size_t)T_ * D_);
  unsigned short* hbT = hb + (size_t)T_ * D_;
  unsigned short* gb  = hbT + (size_t)T_ * D_;
  unsigned short* W   = gb + (size_t)T_ * D_;                  // [T*T] bf16

  hipMemsetAsync(L, 0, 2 * (size_t)T_ * sizeof(float), stream);  // L + dmaxu only

  k_prep<<<T_, 256, 0, stream>>>(x, invnorm, hb);
  k_transp<<<dim3(T_ / 32, D_ / 32), 256, 0, stream>>>(hb, hbT);
  k_gemm1<<<1056, 256, 0, stream>>>(hb, W, L);
  k_gemm2<<<dim3(64, 7, 4), 256, 0, stream>>>(W, hbT, gpart);
  k_gfin<<<T_, 256, 0, stream>>>(gpart, L, x, invnorm, gb, gn2, dist2);
  k_gemm3<<<1056, 256, 0, stream>>>(gb, hb, gn2, dmaxu);
  k_final<<<(T_ + 255) / 256, 256, 0, stream>>>(m_t, c_t, d_t, mu, dist2, dmaxu, out);
}